// Round 2
// baseline (1172.644 us; speedup 1.0000x reference)
//
#include <hip/hip_runtime.h>
#include <cstdint>
#include <cstddef>

// GAT forward: query = ufea@W^T + b; S = leaky2((q@inter^T)/sqrt(D)) masked by adj;
// out = softmax(S) @ inter.   N=10000 users, M=12000 items, D=128.
// bf16 MFMA flash-style single pass (no max subtraction needed: |scores|<~6).
// R2: latency fix — coalesced dwordx4 adj loads software-pipelined one full tile
// ahead, masks staged per-wave in LDS (packed bytes), NO __syncthreads in K-loop
// (P and mask buffers are per-wave; DS pipe is in-order within a wave).

#define N_USERS 10000
#define N_ITEMS 12000
#define HD      128
#define QROWS   10048      // 157*64 padded user rows
#define NCHUNK  8
#define NTILES  188        // ceil(12000/64); tile 187 has 32 valid items
#define UBLOCKS 157
#define KT_PITCH 12032     // interT row pitch (pad so tail-tile reads stay in-buffer)

typedef __bf16 bf16x8 __attribute__((ext_vector_type(8)));
typedef __bf16 bf16x4 __attribute__((ext_vector_type(4)));
typedef float  f32x4  __attribute__((ext_vector_type(4)));
typedef int    i32x4  __attribute__((ext_vector_type(4)));

// ---------------- inter -> bf16 (row-major) + bf16 transposed copy ----------------
__global__ __launch_bounds__(256) void cast_inter_kernel(const float* __restrict__ inter,
                                                         __bf16* __restrict__ kg,
                                                         __bf16* __restrict__ ktg) {
    __shared__ __bf16 Tl[128 * 72];   // [d][item_local], pitch 72 (16B-aligned rows)
    const int t  = threadIdx.x;
    const int i0 = blockIdx.x * 64;
    for (int it = 0; it < 8; ++it) {
        int g   = it * 256 + t;
        int row = g >> 5;            // 0..63 item_local
        int d   = (g & 31) * 4;      // 0..124
        int item = i0 + row;
        if (item < N_ITEMS) {
            f32x4 v = *(const f32x4*)(inter + (size_t)item * HD + d);
            __bf16 b0 = (__bf16)v.x, b1 = (__bf16)v.y, b2 = (__bf16)v.z, b3 = (__bf16)v.w;
            bf16x4 pk = {b0, b1, b2, b3};
            *(bf16x4*)(kg + (size_t)item * HD + d) = pk;
            Tl[(d + 0) * 72 + row] = b0;
            Tl[(d + 1) * 72 + row] = b1;
            Tl[(d + 2) * 72 + row] = b2;
            Tl[(d + 3) * 72 + row] = b3;
        } else {
            Tl[(d + 0) * 72 + row] = (__bf16)0.f;
            Tl[(d + 1) * 72 + row] = (__bf16)0.f;
            Tl[(d + 2) * 72 + row] = (__bf16)0.f;
            Tl[(d + 3) * 72 + row] = (__bf16)0.f;
        }
    }
    __syncthreads();
    const int d  = t >> 1;
    const int jb = (t & 1) * 32;
    if (i0 + jb < N_ITEMS) {          // 12000 % 32 == 0 so validity is per-half
        #pragma unroll
        for (int k = 0; k < 4; ++k) {
            bf16x8 v = *(const bf16x8*)&Tl[d * 72 + jb + k * 8];
            *(bf16x8*)(ktg + (size_t)d * KT_PITCH + i0 + jb + k * 8) = v;
        }
    }
}

// ---------------- query = ufea @ W^T + b  (bf16 MFMA, output bf16) ----------------
__global__ __launch_bounds__(256) void query_kernel(const float* __restrict__ ufea,
                                                    const float* __restrict__ W,
                                                    const float* __restrict__ bias,
                                                    __bf16* __restrict__ qg) {
    const int lane = threadIdx.x & 63, wave = threadIdx.x >> 6;
    const int n = lane & 15, qd = lane >> 4;
    const int user0 = blockIdx.x * 64 + wave * 16;
    int arow = user0 + n; if (arow > N_USERS - 1) arow = N_USERS - 1;

    bf16x8 af[4];
    #pragma unroll
    for (int kk = 0; kk < 4; ++kk) {
        const float* p = ufea + (size_t)arow * HD + kk * 32 + qd * 8;
        f32x4 lo = *(const f32x4*)p, hi = *(const f32x4*)(p + 4);
        bf16x8 a;
        a[0]=(__bf16)lo.x; a[1]=(__bf16)lo.y; a[2]=(__bf16)lo.z; a[3]=(__bf16)lo.w;
        a[4]=(__bf16)hi.x; a[5]=(__bf16)hi.y; a[6]=(__bf16)hi.z; a[7]=(__bf16)hi.w;
        af[kk] = a;
    }
    #pragma unroll
    for (int nt = 0; nt < 8; ++nt) {
        f32x4 acc = {0.f, 0.f, 0.f, 0.f};
        #pragma unroll
        for (int kk = 0; kk < 4; ++kk) {
            const float* p = W + (size_t)(nt * 16 + n) * HD + kk * 32 + qd * 8;
            f32x4 lo = *(const f32x4*)p, hi = *(const f32x4*)(p + 4);
            bf16x8 b;
            b[0]=(__bf16)lo.x; b[1]=(__bf16)lo.y; b[2]=(__bf16)lo.z; b[3]=(__bf16)lo.w;
            b[4]=(__bf16)hi.x; b[5]=(__bf16)hi.y; b[6]=(__bf16)hi.z; b[7]=(__bf16)hi.w;
            acc = __builtin_amdgcn_mfma_f32_16x16x32_bf16(af[kk], b, acc, 0, 0, 0);
        }
        const float bv = bias[nt * 16 + n];
        #pragma unroll
        for (int r = 0; r < 4; ++r) {
            int row = user0 + qd * 4 + r;   // always < QROWS; pad rows hold clamped dup (unused)
            qg[(size_t)row * HD + nt * 16 + n] = (__bf16)(acc[r] + bv);
        }
    }
}

// ---------------- fused: S = q@k^T, mask+leaky+exp, O += P@V, l += rowsum ----------------
// Per-wave LDS only; no block barriers in the K-loop. adj prefetched one tile ahead.
__global__ __launch_bounds__(256) void fused_kernel(const __bf16* __restrict__ qg,
                                                    const __bf16* __restrict__ kg,
                                                    const __bf16* __restrict__ ktg,
                                                    const int* __restrict__ adj,
                                                    float* __restrict__ Opart,
                                                    float* __restrict__ lpart) {
    __shared__ __bf16 Pl[4][16 * 72];        // per-wave P buffer, row pitch 72 (b128-aligned)
    __shared__ unsigned int Al[4][64 * 5];   // per-wave packed masks: [col][rows/4], pitch 5 dwords
    const int lane = threadIdx.x & 63, wave = threadIdx.x >> 6;
    const int n = lane & 15, qd = lane >> 4;   // also: adj rows qd*4..+3, col base n*4
    const int user0 = blockIdx.x * 64 + wave * 16;
    const int chunk = blockIdx.y;
    const int t0 = (chunk * NTILES) / NCHUNK;
    const int t1 = ((chunk + 1) * NTILES) / NCHUNK;
    const float SC = (float)(1.4426950408889634 * 0.08838834764831845); // log2(e)/sqrt(128)

    bf16x8 qf[4];
    #pragma unroll
    for (int kk = 0; kk < 4; ++kk)
        qf[kk] = *(const bf16x8*)(qg + (size_t)(user0 + n) * HD + kk * 32 + qd * 8);

    f32x4 Oacc[8];
    #pragma unroll
    for (int dt = 0; dt < 8; ++dt) Oacc[dt] = (f32x4){0.f, 0.f, 0.f, 0.f};
    float lacc[4] = {0.f, 0.f, 0.f, 0.f};

    size_t adjOff[4];
    #pragma unroll
    for (int r = 0; r < 4; ++r) {
        int u = user0 + qd * 4 + r;
        if (u > N_USERS - 1) u = N_USERS - 1;
        adjOff[r] = (size_t)u * N_ITEMS;
    }
    __bf16* pw = &Pl[wave][0];
    unsigned int* aw = &Al[wave][0];

    // prologue: adj tile t0 into registers (coalesced dwordx4, 4 rows each)
    i32x4 av[4];
    {
        int c = t0 * 64 + n * 4; if (c > N_ITEMS - 4) c = N_ITEMS - 4;
        #pragma unroll
        for (int r = 0; r < 4; ++r)
            av[r] = __builtin_nontemporal_load((const i32x4*)(adj + adjOff[r] + c));
    }

    for (int t = t0; t < t1; ++t) {
        const int j0 = t * 64;
        // stage current masks to LDS: pack rows qd*4..+3 per col into one dword
        #pragma unroll
        for (int cc = 0; cc < 4; ++cc) {
            unsigned int packed = (unsigned int)av[0][cc] | ((unsigned int)av[1][cc] << 8)
                                | ((unsigned int)av[2][cc] << 16) | ((unsigned int)av[3][cc] << 24);
            aw[(n * 4 + cc) * 5 + qd] = packed;
        }
        // prefetch next tile's adj (register pipeline — full tile of latency hiding)
        if (t + 1 < t1) {
            int c = (t + 1) * 64 + n * 4; if (c > N_ITEMS - 4) c = N_ITEMS - 4;
            #pragma unroll
            for (int r = 0; r < 4; ++r)
                av[r] = __builtin_nontemporal_load((const i32x4*)(adj + adjOff[r] + c));
        }

        // S = q @ K^T (16 MFMAs)
        f32x4 S[4];
        #pragma unroll
        for (int nt = 0; nt < 4; ++nt) S[nt] = (f32x4){0.f, 0.f, 0.f, 0.f};
        #pragma unroll
        for (int nt = 0; nt < 4; ++nt) {
            int krow = j0 + nt * 16 + n; if (krow > N_ITEMS - 1) krow = N_ITEMS - 1;
            const __bf16* kp = kg + (size_t)krow * HD + qd * 8;
            #pragma unroll
            for (int kk = 0; kk < 4; ++kk) {
                bf16x8 b = *(const bf16x8*)(kp + kk * 32);
                S[nt] = __builtin_amdgcn_mfma_f32_16x16x32_bf16(qf[kk], b, S[nt], 0, 0, 0);
            }
        }
        // mask + leaky2 + exp2 -> P (bf16 in per-wave LDS), l accumulation
        #pragma unroll
        for (int nt = 0; nt < 4; ++nt) {
            const int col = j0 + nt * 16 + n;
            const bool cv = col < N_ITEMS;
            const unsigned int m = aw[(nt * 16 + n) * 5 + qd];
            #pragma unroll
            for (int r = 0; r < 4; ++r) {
                float s = S[nt][r] * SC;
                s = fminf(s, s + s);                      // leaky_relu(slope 2), pre-scaled
                const bool on = cv && ((m >> (8 * r)) & 1u);
                float p = on ? __builtin_amdgcn_exp2f(s) : 0.f;
                lacc[r] += p;
                pw[(qd * 4 + r) * 72 + nt * 16 + n] = (__bf16)p;
            }
        }
        // P (C-layout) -> A-layout via per-wave LDS; PV (16 MFMAs)
        #pragma unroll
        for (int kc = 0; kc < 2; ++kc) {
            bf16x8 af = *(const bf16x8*)(pw + n * 72 + kc * 32 + qd * 8);
            #pragma unroll
            for (int dt = 0; dt < 8; ++dt) {
                bf16x8 b = *(const bf16x8*)(ktg + (size_t)(dt * 16 + n) * KT_PITCH + j0 + kc * 32 + qd * 8);
                Oacc[dt] = __builtin_amdgcn_mfma_f32_16x16x32_bf16(af, b, Oacc[dt], 0, 0, 0);
            }
        }
    }

    // reduce l across the 16 lanes of each quad (each lane covered cols == n mod 16)
    #pragma unroll
    for (int r = 0; r < 4; ++r) {
        float v = lacc[r];
        v += __shfl_xor(v, 1);
        v += __shfl_xor(v, 2);
        v += __shfl_xor(v, 4);
        v += __shfl_xor(v, 8);
        lacc[r] = v;
    }
    const size_t cb = (size_t)chunk * QROWS;
    #pragma unroll
    for (int r = 0; r < 4; ++r) {
        const int user = user0 + qd * 4 + r;
        if (user < N_USERS) {
            #pragma unroll
            for (int dt = 0; dt < 8; ++dt)
                Opart[(cb + user) * HD + dt * 16 + n] = Oacc[dt][r];
            if (n == 0) lpart[cb + user] = lacc[r];
        }
    }
}

// ---------------- combine partials: out = (sum_c O_c) / (sum_c l_c) ----------------
__global__ __launch_bounds__(256) void combine_kernel(const float* __restrict__ Opart,
                                                      const float* __restrict__ lpart,
                                                      float* __restrict__ out) {
    const int g = blockIdx.x * 256 + threadIdx.x;   // 320000 threads exactly
    const int base = g * 4;
    const int user = base >> 7;
    const int d = base & 127;
    f32x4 acc = {0.f, 0.f, 0.f, 0.f};
    float l = 0.f;
    #pragma unroll
    for (int c = 0; c < NCHUNK; ++c) {
        acc += *(const f32x4*)(Opart + ((size_t)c * QROWS + user) * HD + d);
        l += lpart[(size_t)c * QROWS + user];
    }
    f32x4 res = acc / l;
    *(f32x4*)(out + (size_t)user * HD + d) = res;
}

extern "C" void kernel_launch(void* const* d_in, const int* in_sizes, int n_in,
                              void* d_out, int out_size, void* d_ws, size_t ws_size,
                              hipStream_t stream) {
    const float* ufea = (const float*)d_in[0];
    const float* inter = (const float*)d_in[1];
    const int*   adj  = (const int*)d_in[2];
    const float* W    = (const float*)d_in[3];
    const float* bias = (const float*)d_in[4];
    float* out = (float*)d_out;

    char* ws = (char*)d_ws;
    // layout (bytes, all 256-aligned):
    //   qg    : 10048*128*2      = 2,572,288
    //   kg    : 12000*128*2      = 3,072,000
    //   ktg   : 128*12032*2      = 3,080,192
    //   Opart : 8*10048*128*4    = 41,156,608
    //   lpart : 8*10048*4        = 321,536          total ~50.2 MB
    __bf16* qg   = (__bf16*)(ws);
    __bf16* kg   = (__bf16*)(ws + 2572288);
    __bf16* ktg  = (__bf16*)(ws + 2572288 + 3072000);
    float*  Opart = (float*)(ws + 2572288 + 3072000 + 3080192);
    float*  lpart = (float*)(ws + 2572288 + 3072000 + 3080192 + 41156608);

    cast_inter_kernel<<<dim3(188), dim3(256), 0, stream>>>(inter, kg, ktg);
    query_kernel<<<dim3(UBLOCKS), dim3(256), 0, stream>>>(ufea, W, bias, qg);
    fused_kernel<<<dim3(UBLOCKS, NCHUNK), dim3(256), 0, stream>>>(qg, kg, ktg, adj, Opart, lpart);
    combine_kernel<<<dim3(1250), dim3(256), 0, stream>>>(Opart, lpart, out);
}

// Round 3
// 725.123 us; speedup vs baseline: 1.6172x; 1.6172x over previous
//
#include <hip/hip_runtime.h>
#include <cstdint>
#include <cstddef>

// GAT forward: query = ufea@W^T + b; S = leaky2((q@inter^T)/sqrt(D)) masked by adj;
// out = softmax(S) @ inter.   N=10000 users, M=12000 items, D=128.
// R3: m97-style LDS staging for K/V tiles via global_load_lds (width=16),
// fragment-order LDS layout (chunk-per-frag, lane*16B) -> stage dest is exactly
// the wave-uniform-base+lane*16 HW pattern, reads are conflict-free ds_read_b128.
// adj stays register-pipelined one tile ahead. 2 barriers/tile, 3 blocks/CU.

#define N_USERS 10000
#define N_ITEMS 12000
#define HD      128
#define QROWS   10048      // 157*64 padded user rows
#define NCHUNK  8
#define NTILES  188        // ceil(12000/64); tile 187 has 32 valid items
#define UBLOCKS 157
#define KT_PITCH 12032     // interT row pitch (pad so tail-tile reads stay in-buffer)

typedef __bf16 bf16x8 __attribute__((ext_vector_type(8)));
typedef __bf16 bf16x4 __attribute__((ext_vector_type(4)));
typedef float  f32x4  __attribute__((ext_vector_type(4)));
typedef int    i32x4  __attribute__((ext_vector_type(4)));

typedef const __attribute__((address_space(1))) unsigned int g_u32;
typedef __attribute__((address_space(3))) unsigned int l_u32;

// ---------------- inter -> bf16 (row-major) + bf16 transposed copy ----------------
__global__ __launch_bounds__(256) void cast_inter_kernel(const float* __restrict__ inter,
                                                         __bf16* __restrict__ kg,
                                                         __bf16* __restrict__ ktg) {
    __shared__ __bf16 Tl[128 * 72];   // [d][item_local], pitch 72 (16B-aligned rows)
    const int t  = threadIdx.x;
    const int i0 = blockIdx.x * 64;
    for (int it = 0; it < 8; ++it) {
        int g   = it * 256 + t;
        int row = g >> 5;            // 0..63 item_local
        int d   = (g & 31) * 4;      // 0..124
        int item = i0 + row;
        if (item < N_ITEMS) {
            f32x4 v = *(const f32x4*)(inter + (size_t)item * HD + d);
            __bf16 b0 = (__bf16)v.x, b1 = (__bf16)v.y, b2 = (__bf16)v.z, b3 = (__bf16)v.w;
            bf16x4 pk = {b0, b1, b2, b3};
            *(bf16x4*)(kg + (size_t)item * HD + d) = pk;
            Tl[(d + 0) * 72 + row] = b0;
            Tl[(d + 1) * 72 + row] = b1;
            Tl[(d + 2) * 72 + row] = b2;
            Tl[(d + 3) * 72 + row] = b3;
        } else {
            Tl[(d + 0) * 72 + row] = (__bf16)0.f;
            Tl[(d + 1) * 72 + row] = (__bf16)0.f;
            Tl[(d + 2) * 72 + row] = (__bf16)0.f;
            Tl[(d + 3) * 72 + row] = (__bf16)0.f;
        }
    }
    __syncthreads();
    const int d  = t >> 1;
    const int jb = (t & 1) * 32;
    if (i0 + jb < N_ITEMS) {          // 12000 % 32 == 0 so validity is per-half
        #pragma unroll
        for (int k = 0; k < 4; ++k) {
            bf16x8 v = *(const bf16x8*)&Tl[d * 72 + jb + k * 8];
            *(bf16x8*)(ktg + (size_t)d * KT_PITCH + i0 + jb + k * 8) = v;
        }
    }
}

// ---------------- query = ufea @ W^T + b  (bf16 MFMA, output bf16) ----------------
__global__ __launch_bounds__(256) void query_kernel(const float* __restrict__ ufea,
                                                    const float* __restrict__ W,
                                                    const float* __restrict__ bias,
                                                    __bf16* __restrict__ qg) {
    const int lane = threadIdx.x & 63, wave = threadIdx.x >> 6;
    const int n = lane & 15, qd = lane >> 4;
    const int user0 = blockIdx.x * 64 + wave * 16;
    int arow = user0 + n; if (arow > N_USERS - 1) arow = N_USERS - 1;

    bf16x8 af[4];
    #pragma unroll
    for (int kk = 0; kk < 4; ++kk) {
        const float* p = ufea + (size_t)arow * HD + kk * 32 + qd * 8;
        f32x4 lo = *(const f32x4*)p, hi = *(const f32x4*)(p + 4);
        bf16x8 a;
        a[0]=(__bf16)lo.x; a[1]=(__bf16)lo.y; a[2]=(__bf16)lo.z; a[3]=(__bf16)lo.w;
        a[4]=(__bf16)hi.x; a[5]=(__bf16)hi.y; a[6]=(__bf16)hi.z; a[7]=(__bf16)hi.w;
        af[kk] = a;
    }
    #pragma unroll
    for (int nt = 0; nt < 8; ++nt) {
        f32x4 acc = {0.f, 0.f, 0.f, 0.f};
        #pragma unroll
        for (int kk = 0; kk < 4; ++kk) {
            const float* p = W + (size_t)(nt * 16 + n) * HD + kk * 32 + qd * 8;
            f32x4 lo = *(const f32x4*)p, hi = *(const f32x4*)(p + 4);
            bf16x8 b;
            b[0]=(__bf16)lo.x; b[1]=(__bf16)lo.y; b[2]=(__bf16)lo.z; b[3]=(__bf16)lo.w;
            b[4]=(__bf16)hi.x; b[5]=(__bf16)hi.y; b[6]=(__bf16)hi.z; b[7]=(__bf16)hi.w;
            acc = __builtin_amdgcn_mfma_f32_16x16x32_bf16(af[kk], b, acc, 0, 0, 0);
        }
        const float bv = bias[nt * 16 + n];
        #pragma unroll
        for (int r = 0; r < 4; ++r) {
            int row = user0 + qd * 4 + r;   // always < QROWS; pad rows hold clamped dup (unused)
            qg[(size_t)row * HD + nt * 16 + n] = (__bf16)(acc[r] + bv);
        }
    }
}

// ---------------- fused: S = q@k^T, mask+leaky+exp, O += P@V, l += rowsum ----------------
// K/V tiles staged in LDS (fragment-order) via global_load_lds; 2 barriers/tile.
__global__ __launch_bounds__(256) void fused_kernel(const __bf16* __restrict__ qg,
                                                    const __bf16* __restrict__ kg,
                                                    const __bf16* __restrict__ ktg,
                                                    const int* __restrict__ adj,
                                                    float* __restrict__ Opart,
                                                    float* __restrict__ lpart) {
    // Fragment-order staging: chunk c holds one wave-fragment (1 KB), lane i's 16B
    // at chunk_base + i*16 — exactly global_load_lds's wave-uniform-base + lane*16.
    __shared__ __bf16 Kbuf[16 * 512];        // 16 KB: chunk c=(nt*4+kk) -> K[j0+nt*16+n][kk*32+qd*8..]
    __shared__ __bf16 Vbuf[16 * 512];        // 16 KB: chunk c=(dt*2+kc) -> V_T[dt*16+n][j0+kc*32+qd*8..]
    __shared__ __bf16 Pl[4][16 * 72];        // per-wave P buffer, row pitch 72 (b128-aligned)
    __shared__ unsigned int Al[4][272];      // per-wave packed masks: [qd][col], pitch 68 dwords
    const int lane = threadIdx.x & 63, wave = threadIdx.x >> 6;
    const int n = lane & 15, qd = lane >> 4;   // also: adj rows qd*4..+3, col base n*4
    const int user0 = blockIdx.x * 64 + wave * 16;
    const int chunk = blockIdx.y;
    const int t0 = (chunk * NTILES) / NCHUNK;
    const int t1 = ((chunk + 1) * NTILES) / NCHUNK;
    const float SC = (float)(1.4426950408889634 * 0.08838834764831845); // log2(e)/sqrt(128)

    bf16x8 qf[4];
    #pragma unroll
    for (int kk = 0; kk < 4; ++kk)
        qf[kk] = *(const bf16x8*)(qg + (size_t)(user0 + n) * HD + kk * 32 + qd * 8);

    f32x4 Oacc[8];
    #pragma unroll
    for (int dt = 0; dt < 8; ++dt) Oacc[dt] = (f32x4){0.f, 0.f, 0.f, 0.f};
    float lacc[4] = {0.f, 0.f, 0.f, 0.f};

    size_t adjOff[4];
    #pragma unroll
    for (int r = 0; r < 4; ++r) {
        int u = user0 + qd * 4 + r;
        if (u > N_USERS - 1) u = N_USERS - 1;
        adjOff[r] = (size_t)u * N_ITEMS;
    }
    __bf16* pw = &Pl[wave][0];
    unsigned int* aw = &Al[wave][0];

    // prologue: adj tile t0 into registers (coalesced dwordx4, 4 rows each)
    i32x4 av[4];
    {
        int c = t0 * 64 + n * 4; if (c > N_ITEMS - 4) c = N_ITEMS - 4;
        #pragma unroll
        for (int r = 0; r < 4; ++r)
            av[r] = __builtin_nontemporal_load((const i32x4*)(adj + adjOff[r] + c));
    }

    for (int t = t0; t < t1; ++t) {
        const int j0 = t * 64;
        __syncthreads();   // previous tile's LDS reads complete in all waves

        // ---- async stage K: wave stages chunks 4w..4w+3 (nt = chunk>>2, kk = chunk&3)
        #pragma unroll
        for (int j = 0; j < 4; ++j) {
            const int c  = wave * 4 + j;
            const int nt = c >> 2, kk = c & 3;
            int item = j0 + nt * 16 + n; if (item > N_ITEMS - 1) item = N_ITEMS - 1;
            const __bf16* src = kg + (size_t)item * HD + kk * 32 + qd * 8;
            __builtin_amdgcn_global_load_lds((g_u32*)src, (l_u32*)(Kbuf + c * 512), 16, 0, 0);
        }
        // ---- async stage V: wave stages chunks 4w..4w+3 (dt = chunk>>1, kc = chunk&1)
        #pragma unroll
        for (int j = 0; j < 4; ++j) {
            const int c  = wave * 4 + j;
            const int dt = c >> 1, kc = c & 1;
            const __bf16* src = ktg + (size_t)(dt * 16 + n) * KT_PITCH + j0 + kc * 32 + qd * 8;
            __builtin_amdgcn_global_load_lds((g_u32*)src, (l_u32*)(Vbuf + c * 512), 16, 0, 0);
        }

        // stage current adj masks to per-wave LDS: packed rows qd*4..+3 per col
        #pragma unroll
        for (int cc = 0; cc < 4; ++cc) {
            unsigned int packed = (unsigned int)av[0][cc] | ((unsigned int)av[1][cc] << 8)
                                | ((unsigned int)av[2][cc] << 16) | ((unsigned int)av[3][cc] << 24);
            aw[qd * 68 + n * 4 + cc] = packed;
        }
        // prefetch next tile's adj (register pipeline — full tile of latency hiding)
        if (t + 1 < t1) {
            int c = (t + 1) * 64 + n * 4; if (c > N_ITEMS - 4) c = N_ITEMS - 4;
            #pragma unroll
            for (int r = 0; r < 4; ++r)
                av[r] = __builtin_nontemporal_load((const i32x4*)(adj + adjOff[r] + c));
        }

        __syncthreads();   // barrier implies vmcnt(0): staged K/V visible

        // S = q @ K^T (16 MFMAs), B-frags from Kbuf (contiguous b128, conflict-free)
        f32x4 S[4];
        #pragma unroll
        for (int nt = 0; nt < 4; ++nt) S[nt] = (f32x4){0.f, 0.f, 0.f, 0.f};
        #pragma unroll
        for (int nt = 0; nt < 4; ++nt) {
            #pragma unroll
            for (int kk = 0; kk < 4; ++kk) {
                bf16x8 b = *(const bf16x8*)(Kbuf + (nt * 4 + kk) * 512 + (qd * 16 + n) * 8);
                S[nt] = __builtin_amdgcn_mfma_f32_16x16x32_bf16(qf[kk], b, S[nt], 0, 0, 0);
            }
        }
        // mask + leaky2 + exp2 -> P (bf16 in per-wave LDS), l accumulation
        #pragma unroll
        for (int nt = 0; nt < 4; ++nt) {
            const int col = j0 + nt * 16 + n;
            const bool cv = col < N_ITEMS;
            const unsigned int m = aw[qd * 68 + nt * 16 + n];
            #pragma unroll
            for (int r = 0; r < 4; ++r) {
                float s = S[nt][r] * SC;
                s = fminf(s, s + s);                      // leaky_relu(slope 2), pre-scaled
                const bool on = cv && ((m >> (8 * r)) & 1u);
                float p = on ? __builtin_amdgcn_exp2f(s) : 0.f;
                lacc[r] += p;
                pw[(qd * 4 + r) * 72 + nt * 16 + n] = (__bf16)p;
            }
        }
        // P (C-layout) -> A-layout via per-wave LDS; PV (16 MFMAs), B-frags from Vbuf
        #pragma unroll
        for (int kc = 0; kc < 2; ++kc) {
            bf16x8 af = *(const bf16x8*)(pw + n * 72 + kc * 32 + qd * 8);
            #pragma unroll
            for (int dt = 0; dt < 8; ++dt) {
                bf16x8 b = *(const bf16x8*)(Vbuf + (dt * 2 + kc) * 512 + (qd * 16 + n) * 8);
                Oacc[dt] = __builtin_amdgcn_mfma_f32_16x16x32_bf16(af, b, Oacc[dt], 0, 0, 0);
            }
        }
    }

    // reduce l across the 16 lanes of each quad (each lane covered cols == n mod 16)
    #pragma unroll
    for (int r = 0; r < 4; ++r) {
        float v = lacc[r];
        v += __shfl_xor(v, 1);
        v += __shfl_xor(v, 2);
        v += __shfl_xor(v, 4);
        v += __shfl_xor(v, 8);
        lacc[r] = v;
    }
    const size_t cb = (size_t)chunk * QROWS;
    #pragma unroll
    for (int r = 0; r < 4; ++r) {
        const int user = user0 + qd * 4 + r;
        if (user < N_USERS) {
            #pragma unroll
            for (int dt = 0; dt < 8; ++dt)
                Opart[(cb + user) * HD + dt * 16 + n] = Oacc[dt][r];
            if (n == 0) lpart[cb + user] = lacc[r];
        }
    }
}

// ---------------- combine partials: out = (sum_c O_c) / (sum_c l_c) ----------------
__global__ __launch_bounds__(256) void combine_kernel(const float* __restrict__ Opart,
                                                      const float* __restrict__ lpart,
                                                      float* __restrict__ out) {
    const int g = blockIdx.x * 256 + threadIdx.x;   // 320000 threads exactly
    const int base = g * 4;
    const int user = base >> 7;
    const int d = base & 127;
    f32x4 acc = {0.f, 0.f, 0.f, 0.f};
    float l = 0.f;
    #pragma unroll
    for (int c = 0; c < NCHUNK; ++c) {
        acc += *(const f32x4*)(Opart + ((size_t)c * QROWS + user) * HD + d);
        l += lpart[(size_t)c * QROWS + user];
    }
    f32x4 res = acc / l;
    *(f32x4*)(out + (size_t)user * HD + d) = res;
}

extern "C" void kernel_launch(void* const* d_in, const int* in_sizes, int n_in,
                              void* d_out, int out_size, void* d_ws, size_t ws_size,
                              hipStream_t stream) {
    const float* ufea = (const float*)d_in[0];
    const float* inter = (const float*)d_in[1];
    const int*   adj  = (const int*)d_in[2];
    const float* W    = (const float*)d_in[3];
    const float* bias = (const float*)d_in[4];
    float* out = (float*)d_out;

    char* ws = (char*)d_ws;
    // layout (bytes, all 256-aligned):
    //   qg    : 10048*128*2      = 2,572,288
    //   kg    : 12000*128*2      = 3,072,000
    //   ktg   : 128*12032*2      = 3,080,192
    //   Opart : 8*10048*128*4    = 41,156,608
    //   lpart : 8*10048*4        = 321,536          total ~50.2 MB
    __bf16* qg   = (__bf16*)(ws);
    __bf16* kg   = (__bf16*)(ws + 2572288);
    __bf16* ktg  = (__bf16*)(ws + 2572288 + 3072000);
    float*  Opart = (float*)(ws + 2572288 + 3072000 + 3080192);
    float*  lpart = (float*)(ws + 2572288 + 3072000 + 3080192 + 41156608);

    cast_inter_kernel<<<dim3(188), dim3(256), 0, stream>>>(inter, kg, ktg);
    query_kernel<<<dim3(UBLOCKS), dim3(256), 0, stream>>>(ufea, W, bias, qg);
    fused_kernel<<<dim3(UBLOCKS, NCHUNK), dim3(256), 0, stream>>>(qg, kg, ktg, adj, Opart, lpart);
    combine_kernel<<<dim3(1250), dim3(256), 0, stream>>>(Opart, lpart, out);
}